// Round 7
// baseline (224.647 us; speedup 1.0000x reference)
//
#include <hip/hip_runtime.h>
#include <hip/hip_bf16.h>
#include <hip/hip_fp8.h>

typedef __attribute__((ext_vector_type(4))) int i32x4;
typedef __attribute__((ext_vector_type(8))) int i32x8;
typedef __attribute__((ext_vector_type(16))) float f32x16;

#define MARGIN 0.3f
#define BIGF 3.0e38f

__device__ __forceinline__ f32x16 mx_mfma(i32x8 a, i32x8 b, f32x16 c) {
    return __builtin_amdgcn_mfma_scale_f32_32x32x64_f8f6f4(
        a, b, c, 0 /*A fmt fp8*/, 0 /*B fmt fp8*/,
        0, 127 /*scale A = 2^0*/, 0, 127 /*scale B = 2^0*/);
}

// 32B fragment load (one cell slice for this lane): two dwordx4.
__device__ __forceinline__ i32x8 ld32(const unsigned char* p) {
    i32x4 lo = *(const i32x4*)p;
    i32x4 hi = *(const i32x4*)(p + 16);
    return __builtin_shufflevector(lo, hi, 0, 1, 2, 3, 4, 5, 6, 7);
}

// Wave-per-row convert: fp32 -> fp8 e4m3 (OCP) cast, fp32 row norm of the
// fp8-ROUNDED values (consistent with MFMA dots -> exact diagonal), init
// ap/an/cnt. Output in FRAGMENT-NATIVE tiled layout Xf[p][t][l][32B]:
// row = p*32 + (l&31), k = t*64 + (l>>5)*32 + byte. Cell (p,t) = 2 KB
// contiguous = one wave MFMA operand fragment. (R4-verified; UNCHANGED.)
__global__ __launch_bounds__(256) void convert_norm_kernel(
    const float* __restrict__ X, unsigned char* __restrict__ Xf,
    float* __restrict__ nrm, unsigned* __restrict__ ap,
    unsigned* __restrict__ an, unsigned* __restrict__ cnt, int K) {
    const int wave = threadIdx.x >> 6, lane = threadIdx.x & 63;
    const int row = blockIdx.x * 4 + wave;
    const float* xr = X + (size_t)row * K;
    const size_t pbase = ((size_t)(row >> 5)) << 16;  // p * 65536
    const int rsub = row & 31;
    float s = 0.0f;
    for (int c = lane * 8; c < K; c += 64 * 8) {
        float4 v0 = *(const float4*)(xr + c);
        float4 v1 = *(const float4*)(xr + c + 4);
        float f[8] = {v0.x, v0.y, v0.z, v0.w, v1.x, v1.y, v1.z, v1.w};
        union { unsigned char b[8]; uint2 u; } p;
#pragma unroll
        for (int i = 0; i < 8; i++) {
            __hip_fp8_e4m3 q(f[i]);       // OCP e4m3, RNE+saturate
            p.b[i] = q.__x;
            float d = (float)q;           // decoded value
            s += d * d;
        }
        // Fragment-native address: cell (row>>5, c>>6), lane-slot
        // rsub + 32*((c>>5)&1), byte c&31 (multiple of 8 -> aligned uint2).
        const int lslot = rsub + (((c >> 5) & 1) << 5);
        unsigned char* dst = Xf + pbase + ((size_t)(c >> 6) << 11)
                             + (lslot << 5) + (c & 31);
        *(uint2*)dst = p.u;
    }
    for (int off = 32; off > 0; off >>= 1) s += __shfl_xor(s, off, 64);
    if (lane == 0) {
        nrm[row] = s;
        ap[row] = 0u;           // dist_ap >= 0 always (self is a positive)
        an[row] = 0x7F800000u;  // +inf
        if (row == 0) *cnt = 0u;
    }
}

// FULL-SQUARE fp8-MX GEMM-reduce, register dataflow v3 (3-deep pipeline).
// R6 was an infra failure (container), not a kernel result — resubmitted
// unchanged. R5 post-mortem: top-5-by-duration showed COLD early
// dispatches (_ord 2..19, 115 us) while wall improved 132.9->128.6 with
// convert unchanged -> R5's steady-state gemm ~62 us, best so far; the
// profile outliers are cold-cache latency sensitivity of the no-LDS
// design. Limiter model: Xf (8 MB) is LLC-resident with 4x L2 overfetch
// (FETCH 33 MB) -> misses cost 400-600 cy; 2-deep buffering gives only
// ~550 SIMD-cy of cover at 2 waves/SIMD -> matrix pipe stalls on L2-miss
// bursts.
// v3 change (single lever): pipeline depth 2 -> 3. Rotation MM(b) ->
// LD(b, t+3) gives each buffer two full MM phases (~1100 cy) of latency
// cover, enough for an LLC round-trip. Register cost: 3 buffers x 48 +
// 128 acc + addressing ~= 300/wave, trivially fits at 2 waves/SIMD
// (1024-reg budget). Accumulation order stays t-ascending per acc ->
// bit-identical numerics.
// Geometry (R5-verified): block 256x128, 4 waves, wave tile 64x128 = 2x4
// subtiles of 32x32x64 mfma_scale; grid 16x32 = 512 = exactly 2/CU.
// Carried verbatim: fragment-native cells (2 KB, lane l reads its 32 B at
// l*32 via two dwordx4), C/D map col=lane&31 row=(reg&3)+8*(reg>>2)+4*h,
// in-wave row reduction + direct monotone uint atomics, fused last-block
// loss.
__global__ __launch_bounds__(256, 2) void gemm_reduce_kernel(
    const unsigned char* __restrict__ Xf, const float* __restrict__ nrm,
    const int* __restrict__ Y, unsigned* __restrict__ ap,
    unsigned* __restrict__ an, unsigned* __restrict__ cnt,
    float* __restrict__ out, int N, int K) {
    __shared__ int sYr[256], sYc[128];
    __shared__ float sNr[256], sNc[128];
    __shared__ float lsum[4];
    __shared__ unsigned s_done;

    const int tid = threadIdx.x;
    const int wave = tid >> 6;
    const int lane = tid & 63;
    const int m = lane & 31;   // col within 32x32 subtile (outputs)
    const int h = lane >> 5;   // row-group (outputs)

    const int rowBase = (blockIdx.x >> 5) << 8;  // 16 row-blocks of 256
    const int colBase = (blockIdx.x & 31) << 7;  // 32 col-blocks of 128

    if (tid < 256) {
        sYr[tid] = Y[rowBase + tid];
        sNr[tid] = nrm[rowBase + tid];
    }
    if (tid < 128) {
        sYc[tid] = Y[colBase + tid];
        sNc[tid] = nrm[colBase + tid];
    }

    f32x16 acc[2][4];
#pragma unroll
    for (int si = 0; si < 2; si++)
#pragma unroll
        for (int sj = 0; sj < 4; sj++)
#pragma unroll
            for (int rr = 0; rr < 16; rr++) acc[si][sj][rr] = 0.0f;

    // Fragment base pointers. Panel p = global_row/32; cell (p,t) at
    // p*65536 + t*2048; this lane's 32 B at + lane*32. Wave owns A panels
    // rowBase/32 + wave*2 + {0,1}; block shares B panels colBase/32+{0..3}.
    const unsigned char* pa[2];
    const unsigned char* pb[4];
#pragma unroll
    for (int si = 0; si < 2; si++)
        pa[si] = Xf + (((size_t)(rowBase >> 5) + wave * 2 + si) << 16) + lane * 32;
#pragma unroll
    for (int sj = 0; sj < 4; sj++)
        pb[sj] = Xf + (((size_t)(colBase >> 5) + sj) << 16) + lane * 32;

    i32x8 A0[2], B0[4], A1[2], B1[4], A2[2], B2[4];

#define LD(Ab, Bb, t)                                                   \
    do {                                                                \
        const size_t _o = (size_t)(t) << 11;                            \
        _Pragma("unroll") for (int _i = 0; _i < 2; _i++)                \
            Ab[_i] = ld32(pa[_i] + _o);                                 \
        _Pragma("unroll") for (int _j = 0; _j < 4; _j++)                \
            Bb[_j] = ld32(pb[_j] + _o);                                 \
    } while (0)

#define MM(Ab, Bb)                                                      \
    do {                                                                \
        _Pragma("unroll") for (int _i = 0; _i < 2; _i++)                \
            _Pragma("unroll") for (int _j = 0; _j < 4; _j++)            \
                acc[_i][_j] = mx_mfma(Ab[_i], Bb[_j], acc[_i][_j]);     \
    } while (0)

    const int nt = K >> 6;  // 32 k64-steps (nt >= 6 assumed)
    // Prologue: prime 3 buffers.
    LD(A0, B0, 0);
    LD(A1, B1, 1);
    LD(A2, B2, 2);
    int t = 0;
    // Steady state: consume buffer, immediately refill it 3 steps ahead.
    // At MM(A0,t): 24 younger loads (A1,A2) outstanding -> A0's loads
    // landed ~2 MM-phases ago.
    for (; t + 5 < nt; t += 3) {
        MM(A0, B0);
        LD(A0, B0, t + 3);
        MM(A1, B1);
        LD(A1, B1, t + 4);
        MM(A2, B2);
        LD(A2, B2, t + 5);
    }
    // Tail: remaining steps r = nt - t in {3,4,5}; guards are uniform.
    // For nt=32: loop exits at t=27 (r=5) -> MM27, LD30, MM28, LD31,
    // MM29, MM30, MM31.
    MM(A0, B0);
    if (t + 3 < nt) LD(A0, B0, t + 3);
    MM(A1, B1);
    if (t + 4 < nt) LD(A1, B1, t + 4);
    MM(A2, B2);
    if (t + 3 < nt) MM(A0, B0);
    if (t + 4 < nt) MM(A1, B1);

#undef LD
#undef MM

    __syncthreads();  // sY/sN visible (no earlier barrier needed)

    // Epilogue: each wave owns rows rowBase + wave*64 + row64 across the
    // block's full 128 cols. C/D: col = sj*32 + m, row64 = si*32 +
    // (reg&3) + 8*(reg>>2) + 4*h.
#pragma unroll
    for (int si = 0; si < 2; si++)
#pragma unroll
        for (int reg = 0; reg < 16; reg++) {
            const int row64 = si * 32 + (reg & 3) + 8 * (reg >> 2) + 4 * h;
            const int rIdx = wave * 64 + row64;  // row within block tile
            const int yr = sYr[rIdx];
            const float nr = sNr[rIdx];
            float dp = -1.0f, dn = BIGF;
#pragma unroll
            for (int sj = 0; sj < 4; sj++) {
                const int cIdx = sj * 32 + m;
                float d2 = nr + sNc[cIdx] - 2.0f * acc[si][sj][reg];
                float d = sqrtf(fmaxf(d2, 0.0f));
                bool same = (yr == sYc[cIdx]);
                dp = fmaxf(dp, same ? d : -1.0f);
                dn = fminf(dn, same ? BIGF : d);
            }
            // Reduce over the 32 col-lanes (offsets 1..16 keep h fixed).
            for (int off = 1; off < 32; off <<= 1) {
                dp = fmaxf(dp, __shfl_xor(dp, off, 64));
                dn = fminf(dn, __shfl_xor(dn, off, 64));
            }
            if (m == 0) {  // lanes 0 (h=0) and 32 (h=1): disjoint row64 sets
                atomicMax(&ap[rowBase + rIdx], __float_as_uint(fmaxf(dp, 0.0f)));
                atomicMin(&an[rowBase + rIdx], __float_as_uint(dn));
            }
        }

    // Last block computes the loss (release fence before counter increment;
    // acquire fence + agent-scope atomic loads in the last block).
    __syncthreads();
    if (tid == 0) {
        __threadfence();
        s_done = atomicAdd(cnt, 1u);
    }
    __syncthreads();
    if (s_done == gridDim.x - 1) {
        __threadfence();
        float s = 0.0f;
        for (int i = tid; i < N; i += 256) {
            unsigned ua = __hip_atomic_load(&ap[i], __ATOMIC_RELAXED,
                                            __HIP_MEMORY_SCOPE_AGENT);
            unsigned ub = __hip_atomic_load(&an[i], __ATOMIC_RELAXED,
                                            __HIP_MEMORY_SCOPE_AGENT);
            s += fmaxf(__uint_as_float(ua) - __uint_as_float(ub) + MARGIN, 0.0f);
        }
        for (int off = 32; off > 0; off >>= 1) s += __shfl_xor(s, off, 64);
        if (lane == 0) lsum[wave] = s;
        __syncthreads();
        if (tid == 0)
            out[0] = (lsum[0] + lsum[1] + lsum[2] + lsum[3]) / (float)N;
    }
}

extern "C" void kernel_launch(void* const* d_in, const int* in_sizes, int n_in,
                              void* d_out, int out_size, void* d_ws, size_t ws_size,
                              hipStream_t stream) {
    const float* X = (const float*)d_in[0];
    const int* Y = (const int*)d_in[1];
    float* out = (float*)d_out;
    const int N = in_sizes[1];          // 4096
    const int K = in_sizes[0] / N;      // 2048

    char* ws = (char*)d_ws;
    unsigned char* Xf = (unsigned char*)ws;                         // N*K bytes
    float* nrm = (float*)(ws + (size_t)N * K);
    unsigned* ap = (unsigned*)((char*)nrm + (size_t)N * 4);
    unsigned* an = (unsigned*)((char*)ap + (size_t)N * 4);
    unsigned* cnt = (unsigned*)((char*)an + (size_t)N * 4);

    convert_norm_kernel<<<N / 4, 256, 0, stream>>>(X, Xf, nrm, ap, an, cnt, K);
    const int NBr = N / 256, NBc = N / 128;
    gemm_reduce_kernel<<<NBr * NBc, 256, 0, stream>>>(Xf, nrm, Y, ap, an, cnt,
                                                      out, N, K);
}

// Round 8
// 150.237 us; speedup vs baseline: 1.4953x; 1.4953x over previous
//
#include <hip/hip_runtime.h>
#include <hip/hip_bf16.h>
#include <hip/hip_fp8.h>

typedef __attribute__((ext_vector_type(4))) int i32x4;
typedef __attribute__((ext_vector_type(8))) int i32x8;
typedef __attribute__((ext_vector_type(16))) float f32x16;

#define MARGIN 0.3f
#define BIGF 3.0e38f

__device__ __forceinline__ f32x16 mx_mfma(i32x8 a, i32x8 b, f32x16 c) {
    return __builtin_amdgcn_mfma_scale_f32_32x32x64_f8f6f4(
        a, b, c, 0 /*A fmt fp8*/, 0 /*B fmt fp8*/,
        0, 127 /*scale A = 2^0*/, 0, 127 /*scale B = 2^0*/);
}

// 32B fragment load (one cell slice for this lane): two dwordx4.
__device__ __forceinline__ i32x8 ld32(const unsigned char* p) {
    i32x4 lo = *(const i32x4*)p;
    i32x4 hi = *(const i32x4*)(p + 16);
    return __builtin_shufflevector(lo, hi, 0, 1, 2, 3, 4, 5, 6, 7);
}

// Wave-per-row convert: fp32 -> fp8 e4m3 (OCP) cast, fp32 row norm of the
// fp8-ROUNDED values (consistent with MFMA dots -> exact diagonal), init
// ap/an/cnt. Output in FRAGMENT-NATIVE tiled layout Xf[p][t][l][32B]:
// row = p*32 + (l&31), k = t*64 + (l>>5)*32 + byte. Cell (p,t) = 2 KB
// contiguous = one wave MFMA operand fragment. (R4-verified; UNCHANGED.)
__global__ __launch_bounds__(256) void convert_norm_kernel(
    const float* __restrict__ X, unsigned char* __restrict__ Xf,
    float* __restrict__ nrm, unsigned* __restrict__ ap,
    unsigned* __restrict__ an, unsigned* __restrict__ cnt, int K) {
    const int wave = threadIdx.x >> 6, lane = threadIdx.x & 63;
    const int row = blockIdx.x * 4 + wave;
    const float* xr = X + (size_t)row * K;
    const size_t pbase = ((size_t)(row >> 5)) << 16;  // p * 65536
    const int rsub = row & 31;
    float s = 0.0f;
    for (int c = lane * 8; c < K; c += 64 * 8) {
        float4 v0 = *(const float4*)(xr + c);
        float4 v1 = *(const float4*)(xr + c + 4);
        float f[8] = {v0.x, v0.y, v0.z, v0.w, v1.x, v1.y, v1.z, v1.w};
        union { unsigned char b[8]; uint2 u; } p;
#pragma unroll
        for (int i = 0; i < 8; i++) {
            __hip_fp8_e4m3 q(f[i]);       // OCP e4m3, RNE+saturate
            p.b[i] = q.__x;
            float d = (float)q;           // decoded value
            s += d * d;
        }
        // Fragment-native address: cell (row>>5, c>>6), lane-slot
        // rsub + 32*((c>>5)&1), byte c&31 (multiple of 8 -> aligned uint2).
        const int lslot = rsub + (((c >> 5) & 1) << 5);
        unsigned char* dst = Xf + pbase + ((size_t)(c >> 6) << 11)
                             + (lslot << 5) + (c & 31);
        *(uint2*)dst = p.u;
    }
    for (int off = 32; off > 0; off >>= 1) s += __shfl_xor(s, off, 64);
    if (lane == 0) {
        nrm[row] = s;
        ap[row] = 0u;           // dist_ap >= 0 always (self is a positive)
        an[row] = 0x7F800000u;  // +inf
        if (row == 0) *cnt = 0u;
    }
}

// FULL-SQUARE fp8-MX GEMM-reduce, register dataflow v4 (4-deep, small acc).
// R7 post-mortem: depth-3 at wave tile 64x128 needed ~300 regs/wave but
// launch_bounds(256,2) caps at 256 unified -> compiler spilled a buffer
// (WRITE_SIZE 4 MB -> 320 MB of scratch, gemm 62 -> 155 us). R5's 248
// (120 VGPR + 128 acc AGPR) was already at the cap: depth can only grow
// if acc shrinks.
// v4: (1) wave tile 64x64 (block 128x128, 4 waves 2x2, grid 1024 = 2
// resident/CU x 2 rounds): acc 128 -> 64 AGPRs; buffer = 4 cells = 32
// regs -> DEPTH-4 fits: 64 + 128 + ~25 = 217 < 256. Each buffer gets 3
// MM-phases (~1650 cy) of cover vs ~600 cy LLC round-trip.
// (2) Bijective XCD-chunked swizzle (1024%8==0): xcd = bid&7 owns a
// 16-rowBlk x 8-colBlk sub-grid, iterated colBlk-fastest, so the ~64
// resident blocks/XCD touch 1024 rows + 1024 cols = 4 MB = the per-XCD
// L2 (default mapping touched all 8 MB of A -> the 4x overfetch in
// FETCH_SIZE). Permutation is correctness-neutral: monotone atomics +
// counter-gated loss are order-free.
// Carried verbatim: fragment-native cells (2 KB, lane l reads its 32 B at
// l*32 via two dwordx4), C/D map col=lane&31 row=(reg&3)+8*(reg>>2)+4*h,
// R0-verified redmax/redmin LDS combine epilogue, monotone uint atomics,
// fused last-block loss. Numerics bit-identical (t-ascending per acc).
__global__ __launch_bounds__(256, 2) void gemm_reduce_kernel(
    const unsigned char* __restrict__ Xf, const float* __restrict__ nrm,
    const int* __restrict__ Y, unsigned* __restrict__ ap,
    unsigned* __restrict__ an, unsigned* __restrict__ cnt,
    float* __restrict__ out, int N, int K) {
    __shared__ int sYr[128], sYc[128];
    __shared__ float sNr[128], sNc[128];
    __shared__ float redmax[4][64], redmin[4][64];
    __shared__ float lsum[4];
    __shared__ unsigned s_done;

    const int tid = threadIdx.x;
    const int wave = tid >> 6;
    const int lane = tid & 63;
    const int m = lane & 31;   // col within 32x32 subtile (outputs)
    const int h = lane >> 5;   // row-group (outputs)
    const int wr = wave >> 1;  // wave row (0..1): rows wr*64..+63
    const int wc = wave & 1;   // wave col (0..1): cols wc*64..+63

    // XCD-chunked bijective swizzle over the 32x32 block grid.
    // xcd = bid&7 (hw round-robin); chunk (cr,cc) = (xcd>>2, xcd&3)
    // covers rowBlks cr*16..+15, colBlks cc*8..+7; within-chunk seq
    // iterates colBlk fastest -> resident ~64 blocks/XCD span 8 rowBlks
    // x 8 colBlks = 2 MB + 2 MB = L2-sized working set.
    const int bid = blockIdx.x;
    const int xcd = bid & 7;
    const int seq = bid >> 3;           // 0..127
    const int rb = ((xcd >> 2) << 4) + (seq >> 3);   // 0..31
    const int cb = ((xcd & 3) << 3) + (seq & 7);     // 0..31
    const int rowBase = rb << 7;
    const int colBase = cb << 7;

    if (tid < 128) {
        sYr[tid] = Y[rowBase + tid];
        sNr[tid] = nrm[rowBase + tid];
    } else {
        const int t0 = tid - 128;
        sYc[t0] = Y[colBase + t0];
        sNc[t0] = nrm[colBase + t0];
    }

    f32x16 acc[2][2];
#pragma unroll
    for (int si = 0; si < 2; si++)
#pragma unroll
        for (int sj = 0; sj < 2; sj++)
#pragma unroll
            for (int rr = 0; rr < 16; rr++) acc[si][sj][rr] = 0.0f;

    // Fragment base pointers. Panel p = global_row/32; cell (p,t) at
    // p*65536 + t*2048; this lane's 32 B at + lane*32. Wave (wr,wc) owns
    // A panels rowBase/32 + wr*2 + {0,1}, B panels colBase/32 + wc*2 +
    // {0,1} (shared with the sibling wave in the same row/col -> L1 hits).
    const unsigned char* pa[2];
    const unsigned char* pb[2];
#pragma unroll
    for (int si = 0; si < 2; si++)
        pa[si] = Xf + (((size_t)(rowBase >> 5) + wr * 2 + si) << 16) + lane * 32;
#pragma unroll
    for (int sj = 0; sj < 2; sj++)
        pb[sj] = Xf + (((size_t)(colBase >> 5) + wc * 2 + sj) << 16) + lane * 32;

    i32x8 A0[2], B0[2], A1[2], B1[2], A2[2], B2[2], A3[2], B3[2];

#define LD(Ab, Bb, t)                                                   \
    do {                                                                \
        const size_t _o = (size_t)(t) << 11;                            \
        _Pragma("unroll") for (int _i = 0; _i < 2; _i++)                \
            Ab[_i] = ld32(pa[_i] + _o);                                 \
        _Pragma("unroll") for (int _j = 0; _j < 2; _j++)                \
            Bb[_j] = ld32(pb[_j] + _o);                                 \
    } while (0)

#define MM(Ab, Bb)                                                      \
    do {                                                                \
        _Pragma("unroll") for (int _i = 0; _i < 2; _i++)                \
            _Pragma("unroll") for (int _j = 0; _j < 2; _j++)            \
                acc[_i][_j] = mx_mfma(Ab[_i], Bb[_j], acc[_i][_j]);     \
    } while (0)

    const int nt = K >> 6;  // 32 k64-steps (nt >= 8 assumed)
    // Prologue: prime 4 buffers.
    LD(A0, B0, 0);
    LD(A1, B1, 1);
    LD(A2, B2, 2);
    LD(A3, B3, 3);
    int t = 0;
    // Steady state: consume buffer, refill it 4 steps ahead -> each
    // buffer's loads are covered by 3 MM phases before consumption.
    for (; t + 7 < nt; t += 4) {
        MM(A0, B0);
        LD(A0, B0, t + 4);
        MM(A1, B1);
        LD(A1, B1, t + 5);
        MM(A2, B2);
        LD(A2, B2, t + 6);
        MM(A3, B3);
        LD(A3, B3, t + 7);
    }
    // Tail: r = nt - t in {4..7}. For nt=32: loop exits at t=28, r=4 ->
    // exactly MM(A0..A3), no further loads.
    MM(A0, B0);
    if (t + 4 < nt) LD(A0, B0, t + 4);
    MM(A1, B1);
    if (t + 5 < nt) LD(A1, B1, t + 5);
    MM(A2, B2);
    if (t + 6 < nt) LD(A2, B2, t + 6);
    MM(A3, B3);
    if (t + 4 < nt) MM(A0, B0);
    if (t + 5 < nt) MM(A1, B1);
    if (t + 6 < nt) MM(A2, B2);

#undef LD
#undef MM

    __syncthreads();  // sY/sN visible (no earlier barrier in this kernel)

    // Epilogue (R0-verified): C/D col (within subtile) = m, row64 =
    // si*32 + (reg&3) + 8*(reg>>2) + 4*h. Wave covers cols wc*64..+63
    // only -> reduce in-wave, then combine the two wc waves via LDS.
#pragma unroll
    for (int si = 0; si < 2; si++)
#pragma unroll
        for (int reg = 0; reg < 16; reg++) {
            const int row64 = si * 32 + (reg & 3) + 8 * (reg >> 2) + 4 * h;
            const int rIdx = wr * 64 + row64;  // row within block tile
            const int yr = sYr[rIdx];
            const float nr = sNr[rIdx];
            float dp = -1.0f, dn = BIGF;
#pragma unroll
            for (int sj = 0; sj < 2; sj++) {
                const int cIdx = wc * 64 + sj * 32 + m;
                float d2 = nr + sNc[cIdx] - 2.0f * acc[si][sj][reg];
                float d = sqrtf(fmaxf(d2, 0.0f));
                bool same = (yr == sYc[cIdx]);
                dp = fmaxf(dp, same ? d : -1.0f);
                dn = fminf(dn, same ? BIGF : d);
            }
            // Reduce over the 32 col-lanes (offsets 1..16 keep h fixed).
            for (int off = 1; off < 32; off <<= 1) {
                dp = fmaxf(dp, __shfl_xor(dp, off, 64));
                dn = fminf(dn, __shfl_xor(dn, off, 64));
            }
            if (m == 0) {  // lanes 0 (h=0) and 32 (h=1): disjoint row64 sets
                redmax[wave][row64] = dp;
                redmin[wave][row64] = dn;
            }
        }
    __syncthreads();

    // Combine the two wc waves of each wr half; one atomic pair per row.
    // Non-negative floats: uint cmp == float cmp; clamp max to 0 (true
    // dist_ap >= 0 via the diagonal self-pair).
    if (tid < 128) {
        const int wr2 = tid >> 6, r64 = tid & 63;
        float mx = fmaxf(redmax[wr2 * 2][r64], redmax[wr2 * 2 + 1][r64]);
        float mn = fminf(redmin[wr2 * 2][r64], redmin[wr2 * 2 + 1][r64]);
        atomicMax(&ap[rowBase + tid], __float_as_uint(fmaxf(mx, 0.0f)));
        atomicMin(&an[rowBase + tid], __float_as_uint(mn));
    }

    // Last block computes the loss (release fence before counter increment;
    // acquire fence + agent-scope atomic loads in the last block).
    __syncthreads();
    if (tid == 0) {
        __threadfence();
        s_done = atomicAdd(cnt, 1u);
    }
    __syncthreads();
    if (s_done == gridDim.x - 1) {
        __threadfence();
        float s = 0.0f;
        for (int i = tid; i < N; i += 256) {
            unsigned ua = __hip_atomic_load(&ap[i], __ATOMIC_RELAXED,
                                            __HIP_MEMORY_SCOPE_AGENT);
            unsigned ub = __hip_atomic_load(&an[i], __ATOMIC_RELAXED,
                                            __HIP_MEMORY_SCOPE_AGENT);
            s += fmaxf(__uint_as_float(ua) - __uint_as_float(ub) + MARGIN, 0.0f);
        }
        for (int off = 32; off > 0; off >>= 1) s += __shfl_xor(s, off, 64);
        if (lane == 0) lsum[wave] = s;
        __syncthreads();
        if (tid == 0)
            out[0] = (lsum[0] + lsum[1] + lsum[2] + lsum[3]) / (float)N;
    }
}

extern "C" void kernel_launch(void* const* d_in, const int* in_sizes, int n_in,
                              void* d_out, int out_size, void* d_ws, size_t ws_size,
                              hipStream_t stream) {
    const float* X = (const float*)d_in[0];
    const int* Y = (const int*)d_in[1];
    float* out = (float*)d_out;
    const int N = in_sizes[1];          // 4096
    const int K = in_sizes[0] / N;      // 2048

    char* ws = (char*)d_ws;
    unsigned char* Xf = (unsigned char*)ws;                         // N*K bytes
    float* nrm = (float*)(ws + (size_t)N * K);
    unsigned* ap = (unsigned*)((char*)nrm + (size_t)N * 4);
    unsigned* an = (unsigned*)((char*)ap + (size_t)N * 4);
    unsigned* cnt = (unsigned*)((char*)an + (size_t)N * 4);

    convert_norm_kernel<<<N / 4, 256, 0, stream>>>(X, Xf, nrm, ap, an, cnt, K);
    const int NB = N / 128;  // 32x32 block grid, 1024 blocks
    gemm_reduce_kernel<<<NB * NB, 256, 0, stream>>>(Xf, nrm, Y, ap, an, cnt,
                                                    out, N, K);
}

// Round 9
// 133.389 us; speedup vs baseline: 1.6842x; 1.1263x over previous
//
#include <hip/hip_runtime.h>
#include <hip/hip_bf16.h>
#include <hip/hip_fp8.h>

typedef __attribute__((ext_vector_type(4))) int i32x4;
typedef __attribute__((ext_vector_type(8))) int i32x8;
typedef __attribute__((ext_vector_type(16))) float f32x16;

#define MARGIN 0.3f
#define BIGF 3.0e38f

__device__ __forceinline__ f32x16 mx_mfma(i32x8 a, i32x8 b, f32x16 c) {
    return __builtin_amdgcn_mfma_scale_f32_32x32x64_f8f6f4(
        a, b, c, 0 /*A fmt fp8*/, 0 /*B fmt fp8*/,
        0, 127 /*scale A = 2^0*/, 0, 127 /*scale B = 2^0*/);
}

// 32B fragment load (one cell slice for this lane): two dwordx4.
__device__ __forceinline__ i32x8 ld32(const unsigned char* p) {
    i32x4 lo = *(const i32x4*)p;
    i32x4 hi = *(const i32x4*)(p + 16);
    return __builtin_shufflevector(lo, hi, 0, 1, 2, 3, 4, 5, 6, 7);
}

// Wave-per-row convert: fp32 -> fp8 e4m3 (OCP) cast, fp32 row norm of the
// fp8-ROUNDED values (consistent with MFMA dots -> exact diagonal), init
// ap/an/cnt. Output in FRAGMENT-NATIVE tiled layout Xf[p][t][l][32B]:
// row = p*32 + (l&31), k = t*64 + (l>>5)*32 + byte. Cell (p,t) = 2 KB
// contiguous = one wave MFMA operand fragment. (R4-verified; UNCHANGED.)
__global__ __launch_bounds__(256) void convert_norm_kernel(
    const float* __restrict__ X, unsigned char* __restrict__ Xf,
    float* __restrict__ nrm, unsigned* __restrict__ ap,
    unsigned* __restrict__ an, unsigned* __restrict__ cnt, int K) {
    const int wave = threadIdx.x >> 6, lane = threadIdx.x & 63;
    const int row = blockIdx.x * 4 + wave;
    const float* xr = X + (size_t)row * K;
    const size_t pbase = ((size_t)(row >> 5)) << 16;  // p * 65536
    const int rsub = row & 31;
    float s = 0.0f;
    for (int c = lane * 8; c < K; c += 64 * 8) {
        float4 v0 = *(const float4*)(xr + c);
        float4 v1 = *(const float4*)(xr + c + 4);
        float f[8] = {v0.x, v0.y, v0.z, v0.w, v1.x, v1.y, v1.z, v1.w};
        union { unsigned char b[8]; uint2 u; } p;
#pragma unroll
        for (int i = 0; i < 8; i++) {
            __hip_fp8_e4m3 q(f[i]);       // OCP e4m3, RNE+saturate
            p.b[i] = q.__x;
            float d = (float)q;           // decoded value
            s += d * d;
        }
        // Fragment-native address: cell (row>>5, c>>6), lane-slot
        // rsub + 32*((c>>5)&1), byte c&31 (multiple of 8 -> aligned uint2).
        const int lslot = rsub + (((c >> 5) & 1) << 5);
        unsigned char* dst = Xf + pbase + ((size_t)(c >> 6) << 11)
                             + (lslot << 5) + (c & 31);
        *(uint2*)dst = p.u;
    }
    for (int off = 32; off > 0; off >>= 1) s += __shfl_xor(s, off, 64);
    if (lane == 0) {
        nrm[row] = s;
        ap[row] = 0u;           // dist_ap >= 0 always (self is a positive)
        an[row] = 0x7F800000u;  // +inf
        if (row == 0) *cnt = 0u;
    }
}

// TRIANGULAR fp8-MX GEMM-reduce, register dataflow v5.
// R4/R5/R8 established the invariant: the per-CU vector-load return path
// saturates at ~50-62 GB/s regardless of ILP depth (R8 depth-4 == R5
// depth-2 rate) and L2 locality (R8's swizzle cut FETCH 33->21 MB, time
// WORSE); TLP (R4 ~4 blk/CU) buys ~25%. Time ~= delivered-bytes /
// (256 x ~55 GB/s). Only levers left: fewer delivered bytes at >=3-4
// blocks/CU. Register math forbids fatter tiles at 128 regs/wave, so:
// exploit G = X X^T SYMMETRY — compute only j>=i tiles (528 of 1024).
// Halves FLOPs AND delivered bytes. The old triangle objections (2x
// staged bytes, barrier cost, 25% tail in the R0 lockstep design) vanish
// in the no-LDS register dataflow: no staging, no main-loop barriers,
// 528 blocks ~ one resident round at ~4 blk/CU.
// Each off-diag tile feeds BOTH sides: row-side (anchors = tile rows,
// as before) and col-side (anchors = tile cols, candidates = rows) —
// same d values, same label mask, just 2 extra fmax/fmin per element in
// the existing epilogue loop + shfl_xor(32) + a second 128-lane atomic
// pass. Diagonal tiles emit both sides redundantly (harmless: monotone
// max/min of the same value set). Pair (r,c) arithmetic is bit-identical
// to (c,r) (same products, same k-order) -> absmax 0 preserved.
// Geometry: R4's exact main loop (block 128x128, 4 waves 2x2, wave tile
// 64x64, depth-1 compiler-pipelined unroll-4, VGPR ~56 + 64 acc ->
// 4 blk/CU budget). Carried verbatim: fragment-native cells, C/D map
// col=lane&31 row=(reg&3)+8*(reg>>2)+4*h, monotone uint atomics, fused
// last-block loss (gridDim-counter gated).
__global__ __launch_bounds__(256, 4) void gemm_reduce_kernel(
    const unsigned char* __restrict__ Xf, const float* __restrict__ nrm,
    const int* __restrict__ Y, unsigned* __restrict__ ap,
    unsigned* __restrict__ an, unsigned* __restrict__ cnt,
    float* __restrict__ out, int N, int K) {
    __shared__ int sYr[128], sYc[128];
    __shared__ float sNr[128], sNc[128];
    __shared__ float redmax[4][64], redmin[4][64];  // row-side, per wave
    __shared__ float cmax[4][64], cmin[4][64];      // col-side, per wave
    __shared__ float lsum[4];
    __shared__ unsigned s_done;

    const int tid = threadIdx.x;
    const int wave = tid >> 6;
    const int lane = tid & 63;
    const int m = lane & 31;   // col within 32x32 subtile (outputs)
    const int h = lane >> 5;   // row-group (outputs)
    const int wr = wave >> 1;  // wave row (0..1): rows wr*64..+63
    const int wc = wave & 1;   // wave col (0..1): cols wc*64..+63

    // Triangle unrank: blocks enumerate (i,j), j >= i, row-major.
    const int NB = N >> 7;  // 32
    int bi = blockIdx.x, ti = 0;
    while (bi >= NB - ti) { bi -= NB - ti; ti++; }
    const int tj = ti + bi;
    const int rowBase = ti << 7;
    const int colBase = tj << 7;

    if (tid < 128) {
        sYr[tid] = Y[rowBase + tid];
        sNr[tid] = nrm[rowBase + tid];
    } else {
        const int t0 = tid - 128;
        sYc[t0] = Y[colBase + t0];
        sNc[t0] = nrm[colBase + t0];
    }

    f32x16 acc[2][2];
#pragma unroll
    for (int si = 0; si < 2; si++)
#pragma unroll
        for (int sj = 0; sj < 2; sj++)
#pragma unroll
            for (int rr = 0; rr < 16; rr++) acc[si][sj][rr] = 0.0f;

    // Fragment base pointers. Panel p = global_row/32; cell (p,t) at
    // p*65536 + t*2048; this lane's 32 B at + lane*32. Wave (wr,wc) owns
    // A panels rowBase/32 + wr*2 + {0,1}, B panels colBase/32 + wc*2 +
    // {0,1} (each shared with a sibling wave -> L1 temporal hits).
    const unsigned char* pa[2];
    const unsigned char* pb[2];
#pragma unroll
    for (int si = 0; si < 2; si++)
        pa[si] = Xf + (((size_t)(rowBase >> 5) + wr * 2 + si) << 16) + lane * 32;
#pragma unroll
    for (int sj = 0; sj < 2; sj++)
        pb[sj] = Xf + (((size_t)(colBase >> 5) + wc * 2 + sj) << 16) + lane * 32;

    // Main loop: R4-form, depth-1, compiler-pipelined via unroll.
    const int nt = K >> 6;  // 32 k64-steps
#pragma unroll 4
    for (int t = 0; t < nt; t++) {
        const size_t off = (size_t)t << 11;  // t * 2048
        i32x8 a0 = ld32(pa[0] + off);
        i32x8 a1 = ld32(pa[1] + off);
        i32x8 b0 = ld32(pb[0] + off);
        i32x8 b1 = ld32(pb[1] + off);
        acc[0][0] = mx_mfma(a0, b0, acc[0][0]);
        acc[0][1] = mx_mfma(a0, b1, acc[0][1]);
        acc[1][0] = mx_mfma(a1, b0, acc[1][0]);
        acc[1][1] = mx_mfma(a1, b1, acc[1][1]);
    }

    __syncthreads();  // sY/sN visible (no earlier barrier in this kernel)

    // Epilogue, dual-sided. C/D: col (within subtile) = m, row64 =
    // si*32 + (reg&3) + 8*(reg>>2) + 4*h. Row-side: reduce over cols
    // (shfl over 32 m-lanes). Col-side: running per-sj accumulators over
    // (si,reg) — same d, same mask — then combine h-halves via
    // shfl_xor(32).
    float cdp[2] = {-1.0f, -1.0f};
    float cdn[2] = {BIGF, BIGF};
#pragma unroll
    for (int si = 0; si < 2; si++)
#pragma unroll
        for (int reg = 0; reg < 16; reg++) {
            const int row64 = si * 32 + (reg & 3) + 8 * (reg >> 2) + 4 * h;
            const int rIdx = wr * 64 + row64;  // row within block tile
            const int yr = sYr[rIdx];
            const float nr = sNr[rIdx];
            float dp = -1.0f, dn = BIGF;
#pragma unroll
            for (int sj = 0; sj < 2; sj++) {
                const int cIdx = wc * 64 + sj * 32 + m;
                float d2 = nr + sNc[cIdx] - 2.0f * acc[si][sj][reg];
                float d = sqrtf(fmaxf(d2, 0.0f));
                bool same = (yr == sYc[cIdx]);
                float vp = same ? d : -1.0f;
                float vn = same ? BIGF : d;
                dp = fmaxf(dp, vp);
                dn = fminf(dn, vn);
                cdp[sj] = fmaxf(cdp[sj], vp);  // col-side anchor cIdx
                cdn[sj] = fminf(cdn[sj], vn);
            }
            // Row-side: reduce over the 32 col-lanes (h stays fixed).
            for (int off = 1; off < 32; off <<= 1) {
                dp = fmaxf(dp, __shfl_xor(dp, off, 64));
                dn = fminf(dn, __shfl_xor(dn, off, 64));
            }
            if (m == 0) {  // lanes 0 (h=0) and 32 (h=1): disjoint row64 sets
                redmax[wave][row64] = dp;
                redmin[wave][row64] = dn;
            }
        }
    // Col-side: combine the two h-halves (rows +-4 interleave), store.
#pragma unroll
    for (int sj = 0; sj < 2; sj++) {
        cdp[sj] = fmaxf(cdp[sj], __shfl_xor(cdp[sj], 32, 64));
        cdn[sj] = fminf(cdn[sj], __shfl_xor(cdn[sj], 32, 64));
        if (h == 0) {
            cmax[wave][sj * 32 + m] = cdp[sj];
            cmin[wave][sj * 32 + m] = cdn[sj];
        }
    }
    __syncthreads();

    // Combine + atomics. tid<128: row-side (combine the two wc waves of
    // each wr half). tid>=128: col-side (combine the two wr waves of each
    // wc half; wave = wr*2+wc -> waves {wc2, 2+wc2}). Non-negative
    // floats: uint cmp == float cmp; clamp max to 0.
    if (tid < 128) {
        const int wr2 = tid >> 6, r64 = tid & 63;
        float mx = fmaxf(redmax[wr2 * 2][r64], redmax[wr2 * 2 + 1][r64]);
        float mn = fminf(redmin[wr2 * 2][r64], redmin[wr2 * 2 + 1][r64]);
        atomicMax(&ap[rowBase + tid], __float_as_uint(fmaxf(mx, 0.0f)));
        atomicMin(&an[rowBase + tid], __float_as_uint(mn));
    } else {
        const int t0 = tid - 128;
        const int wc2 = t0 >> 6, c64 = t0 & 63;
        float mx = fmaxf(cmax[wc2][c64], cmax[2 + wc2][c64]);
        float mn = fminf(cmin[wc2][c64], cmin[2 + wc2][c64]);
        atomicMax(&ap[colBase + t0], __float_as_uint(fmaxf(mx, 0.0f)));
        atomicMin(&an[colBase + t0], __float_as_uint(mn));
    }

    // Last block computes the loss (release fence before counter increment;
    // acquire fence + agent-scope atomic loads in the last block).
    __syncthreads();
    if (tid == 0) {
        __threadfence();
        s_done = atomicAdd(cnt, 1u);
    }
    __syncthreads();
    if (s_done == gridDim.x - 1) {
        __threadfence();
        float s = 0.0f;
        for (int i = tid; i < N; i += 256) {
            unsigned ua = __hip_atomic_load(&ap[i], __ATOMIC_RELAXED,
                                            __HIP_MEMORY_SCOPE_AGENT);
            unsigned ub = __hip_atomic_load(&an[i], __ATOMIC_RELAXED,
                                            __HIP_MEMORY_SCOPE_AGENT);
            s += fmaxf(__uint_as_float(ua) - __uint_as_float(ub) + MARGIN, 0.0f);
        }
        for (int off = 32; off > 0; off >>= 1) s += __shfl_xor(s, off, 64);
        if (lane == 0) lsum[wave] = s;
        __syncthreads();
        if (tid == 0)
            out[0] = (lsum[0] + lsum[1] + lsum[2] + lsum[3]) / (float)N;
    }
}

extern "C" void kernel_launch(void* const* d_in, const int* in_sizes, int n_in,
                              void* d_out, int out_size, void* d_ws, size_t ws_size,
                              hipStream_t stream) {
    const float* X = (const float*)d_in[0];
    const int* Y = (const int*)d_in[1];
    float* out = (float*)d_out;
    const int N = in_sizes[1];          // 4096
    const int K = in_sizes[0] / N;      // 2048

    char* ws = (char*)d_ws;
    unsigned char* Xf = (unsigned char*)ws;                         // N*K bytes
    float* nrm = (float*)(ws + (size_t)N * K);
    unsigned* ap = (unsigned*)((char*)nrm + (size_t)N * 4);
    unsigned* an = (unsigned*)((char*)ap + (size_t)N * 4);
    unsigned* cnt = (unsigned*)((char*)an + (size_t)N * 4);

    convert_norm_kernel<<<N / 4, 256, 0, stream>>>(X, Xf, nrm, ap, an, cnt, K);
    const int NB = N / 128;                       // 32
    const int ntri = NB * (NB + 1) / 2;           // 528 triangle blocks
    gemm_reduce_kernel<<<ntri, 256, 0, stream>>>(Xf, nrm, Y, ap, an, cnt,
                                                 out, N, K);
}